// Round 4
// baseline (190.560 us; speedup 1.0000x reference)
//
#include <hip/hip_runtime.h>

#define NROWS 32768
#define DDIM  128
#define KCODES 1024
#define DECAY 0.99f
#define OMD   0.01f
#define EPS   1e-5f

typedef __attribute__((ext_vector_type(8))) short short8;
typedef __attribute__((ext_vector_type(4))) float f32x4;

// ws layout (float offsets): [counts 1024][offs i32 1024][cursor i32 1024][inv 1024][en2h 1024][bucket i32 32768]
// offs slot doubles as the int histogram (zeroed by pack_e, atomics from vq_mfma,
// read-then-overwritten per-tid by scan_fin).
#define WS_COUNTS 0
#define WS_OFFS   1024
#define WS_CURSOR 2048
#define WS_INV    3072
#define WS_EN2H   4096
#define WS_BUCKET 5120

__device__ __forceinline__ unsigned int f2bf(float f) {
  union { float f; unsigned int u; } cv; cv.f = f;
  unsigned int u = cv.u;
  return (u + 0x7fffu + ((u >> 16) & 1u)) >> 16;  // RNE
}

__device__ __forceinline__ void gload16(const void* g, void* l) {
  __builtin_amdgcn_global_load_lds(
      (const __attribute__((address_space(1))) unsigned int*)g,
      (__attribute__((address_space(3))) unsigned int*)l, 16, 0, 0);
}

// ---- K1: split embed into (eh, el) bf16, MFMA B-fragment layout + exact norms.
// 64 blocks, one 16-code tile per block, 8 floats per thread.
// epack frag (nt, j): j 0-3 = eh, j 4-7 = el. 512 KB, aliased into out_nea.
// Block 0 also zeroes the int histogram for this iteration. ----
__global__ __launch_bounds__(256) void pack_e(const float* __restrict__ embed,
                                              ushort* __restrict__ epack,
                                              float* __restrict__ en2h,
                                              int* __restrict__ cnt0) {
  const int tid = threadIdx.x;
  const int nt = blockIdx.x;
  if (nt == 0) {
    #pragma unroll
    for (int i = 0; i < 4; ++i) cnt0[tid + i * 256] = 0;
  }
  const int m = tid >> 4, s = tid & 15;     // m = code row in tile, s = k-slot
  const int kb = s >> 2, q = s & 3;
  const int row = nt * 16 + m;
  const float* ep = embed + (size_t)row * DDIM + kb * 32 + q * 8;
  float4 v0 = *(const float4*)(ep);
  float4 v1 = *(const float4*)(ep + 4);
  float v[8] = {v0.x, v0.y, v0.z, v0.w, v1.x, v1.y, v1.z, v1.w};
  unsigned int h[8], l[8];
  float ss = 0.f;
  #pragma unroll
  for (int j = 0; j < 8; ++j) {
    ss += v[j] * v[j];
    h[j] = f2bf(v[j]);
    float fh = __uint_as_float(h[j] << 16);
    l[j] = f2bf(v[j] - fh);
  }
  uint4 ph, pl;
  ph.x = h[0] | (h[1] << 16); ph.y = h[2] | (h[3] << 16);
  ph.z = h[4] | (h[5] << 16); ph.w = h[6] | (h[7] << 16);
  pl.x = l[0] | (l[1] << 16); pl.y = l[2] | (l[3] << 16);
  pl.z = l[4] | (l[5] << 16); pl.w = l[6] | (l[7] << 16);
  *(uint4*)(epack + (((size_t)nt * 8 + kb) * 64 + q * 16 + m) * 8)     = ph;  // eh
  *(uint4*)(epack + (((size_t)nt * 8 + kb + 4) * 64 + q * 16 + m) * 8) = pl;  // el
  // row norm: threads with same m are 16 consecutive lanes (s = lane&15)
  ss += __shfl_xor(ss, 1, 64);
  ss += __shfl_xor(ss, 2, 64);
  ss += __shfl_xor(ss, 4, 64);
  ss += __shfl_xor(ss, 8, 64);
  if (s == 0) en2h[row] = 0.5f * ss;
}

// ---- K2: MFMA scoring + fused quantize write + fused count histogram.
// Block = 128 rows, 4 waves x 2 M-tiles (32 rows/wave). Every wave scans all
// 1024 codes; B tile (8 KB) staged via global_load_lds into a 4-buffer LDS
// ring, depth-3 prefetch, RAW s_barrier + counted vmcnt(4) (T4 pattern --
// NEVER __syncthreads in the loop, its vmcnt(0) drain killed R3).
// 24 MFMAs / 6 independent chains between barriers. LDS-read floor ~10 us. ----
__global__ __launch_bounds__(256, 2) void vq_mfma(
    const float* __restrict__ x, const short8* __restrict__ ep8,
    const float* __restrict__ en2h, const float* __restrict__ embed,
    float* __restrict__ out_ind, float* __restrict__ out_q,
    int* __restrict__ cnt_i) {
  __shared__ short8 bfrag[4][512];          // ring of 4 x 8 KB B tiles
  __shared__ float nlds[KCODES];            // 4 KB staged 0.5*||e||^2
  __shared__ int scodes[128];
  const int tid = threadIdx.x;
  const int w = tid >> 6, lane = tid & 63;
  const int c = lane & 15, q = lane >> 4;
  const int row0 = blockIdx.x * 128;        // block's first x-row

  // (1) global loads for norms + A rows (consumed immediately below)
  float4 nv = *(const float4*)(en2h + tid * 4);

  // A fragments from x rows [row0 + w*32 + t*16, +16): xh 0-3, xl 4-7
  short8 a[2][8];
  #pragma unroll
  for (int t = 0; t < 2; ++t) {
    const float* xp = x + (size_t)(row0 + w * 32 + t * 16 + c) * DDIM + q * 8;
    #pragma unroll
    for (int kb = 0; kb < 4; ++kb) {
      float4 v0 = *(const float4*)(xp + kb * 32);
      float4 v1 = *(const float4*)(xp + kb * 32 + 4);
      float v[8] = {v0.x, v0.y, v0.z, v0.w, v1.x, v1.y, v1.z, v1.w};
      short8 hh, ll;
      #pragma unroll
      for (int j = 0; j < 8; ++j) {
        unsigned int hv = f2bf(v[j]);
        hh[j] = (short)hv;
        float fh = __uint_as_float(hv << 16);
        ll[j] = (short)f2bf(v[j] - fh);
      }
      a[t][kb] = hh;
      a[t][kb + 4] = ll;
    }
  }
  // (2) LDS writes of norms (lgkm traffic, drained before loop)
  *(float4*)(&nlds[tid * 4]) = nv;

  // (3) stage tiles 0..2 -- exactly 6 vmem ops outstanding at loop entry
  #pragma unroll
  for (int p = 0; p < 3; ++p) {
    gload16(ep8 + (size_t)p * 512 + w * 64 + lane, &bfrag[p][w * 64]);
    gload16(ep8 + (size_t)p * 512 + 256 + w * 64 + lane, &bfrag[p][256 + w * 64]);
  }
  // (4) drain LDS writes so first barrier publishes nlds
  asm volatile("s_waitcnt lgkmcnt(0)" ::: "memory");

  float bestv[8]; int besti[8];
  #pragma unroll
  for (int i = 0; i < 8; ++i) { bestv[i] = -3.4e38f; besti[i] = 0; }

  // one code tile: 8 LDS b128 reads feed 24 MFMAs (2 M-tiles x 3 chains)
  auto tile_compute = [&](int nt) {
    const int cur = nt & 3;
    short8 st[8];
    #pragma unroll
    for (int j = 0; j < 8; ++j) st[j] = bfrag[cur][j * 64 + lane];
    const float nh = nlds[nt * 16 + c];
    f32x4 accA0 = {-nh, -nh, -nh, -nh};     // xh . eh (norm folded in)
    f32x4 accA1 = accA0;
    f32x4 accB0 = {0.f, 0.f, 0.f, 0.f};    // xl . eh
    f32x4 accB1 = {0.f, 0.f, 0.f, 0.f};
    f32x4 accC0 = {0.f, 0.f, 0.f, 0.f};    // xh . el
    f32x4 accC1 = {0.f, 0.f, 0.f, 0.f};
    __builtin_amdgcn_s_setprio(1);
    #pragma unroll
    for (int kb = 0; kb < 4; ++kb) {
      accA0 = __builtin_amdgcn_mfma_f32_16x16x32_bf16(a[0][kb],     st[kb],     accA0, 0, 0, 0);
      accA1 = __builtin_amdgcn_mfma_f32_16x16x32_bf16(a[1][kb],     st[kb],     accA1, 0, 0, 0);
      accB0 = __builtin_amdgcn_mfma_f32_16x16x32_bf16(a[0][kb + 4], st[kb],     accB0, 0, 0, 0);
      accB1 = __builtin_amdgcn_mfma_f32_16x16x32_bf16(a[1][kb + 4], st[kb],     accB1, 0, 0, 0);
      accC0 = __builtin_amdgcn_mfma_f32_16x16x32_bf16(a[0][kb],     st[kb + 4], accC0, 0, 0, 0);
      accC1 = __builtin_amdgcn_mfma_f32_16x16x32_bf16(a[1][kb],     st[kb + 4], accC1, 0, 0, 0);
    }
    __builtin_amdgcn_s_setprio(0);
    const int code = nt * 16 + c;
    #pragma unroll
    for (int r = 0; r < 4; ++r) {           // C/D: col(code)=lane&15, row=q*4+r
      float s0 = accA0[r] + accB0[r] + accC0[r];
      if (s0 > bestv[r])     { bestv[r] = s0;     besti[r] = code; }
      float s1 = accA1[r] + accB1[r] + accC1[r];
      if (s1 > bestv[4 + r]) { bestv[4 + r] = s1; besti[4 + r] = code; }
    }
  };

  // main loop: tiles 0..60, staging tile nt+3 each iteration.
  // invariant at loop top: 6 loads outstanding (tiles nt, nt+1, nt+2);
  // vmcnt(4) => own tile-nt chunks landed; raw barrier => everyone's did,
  // and all waves finished reading bfrag[(nt-1)&3] (== the buf we overwrite).
  for (int nt = 0; nt < 61; ++nt) {
    asm volatile("s_waitcnt vmcnt(4)" ::: "memory");
    __builtin_amdgcn_s_barrier();
    __builtin_amdgcn_sched_barrier(0);
    const int bs = (nt + 3) & 3;
    gload16(ep8 + (size_t)(nt + 3) * 512 + w * 64 + lane, &bfrag[bs][w * 64]);
    gload16(ep8 + (size_t)(nt + 3) * 512 + 256 + w * 64 + lane, &bfrag[bs][256 + w * 64]);
    __builtin_amdgcn_sched_barrier(0);
    tile_compute(nt);
  }
  // tail: tiles 61..63, draining 6 -> 4 -> 2 -> 0 outstanding
  asm volatile("s_waitcnt vmcnt(4)" ::: "memory");
  __builtin_amdgcn_s_barrier();
  __builtin_amdgcn_sched_barrier(0);
  tile_compute(61);
  asm volatile("s_waitcnt vmcnt(2)" ::: "memory");
  __builtin_amdgcn_s_barrier();
  __builtin_amdgcn_sched_barrier(0);
  tile_compute(62);
  asm volatile("s_waitcnt vmcnt(0)" ::: "memory");
  __builtin_amdgcn_s_barrier();
  __builtin_amdgcn_sched_barrier(0);
  tile_compute(63);

  // fold across the 16 code-columns (stays within each 16-lane q group)
  #pragma unroll
  for (int off = 1; off < 16; off <<= 1) {
    #pragma unroll
    for (int i = 0; i < 8; ++i) {
      float ov = __shfl_xor(bestv[i], off, 64);
      int   oi = __shfl_xor(besti[i], off, 64);
      if (ov > bestv[i] || (ov == bestv[i] && oi < besti[i])) {
        bestv[i] = ov; besti[i] = oi;       // first-max (lowest idx) ties
      }
    }
  }
  if (c == 0) {                             // 4 writer lanes per wave
    #pragma unroll
    for (int t = 0; t < 2; ++t)
      #pragma unroll
      for (int r = 0; r < 4; ++r) {
        const int row = w * 32 + t * 16 + q * 4 + r;
        const int bi = besti[t * 4 + r];
        out_ind[row0 + row] = (float)bi;
        scodes[row] = bi;
        atomicAdd(&cnt_i[bi], 1);           // fused histogram
      }
  }
  __syncthreads();
  // fused quantize write: 128 rows x 32 float4 = 4096 float4, 16 per thread
  #pragma unroll
  for (int it = 0; it < 16; ++it) {
    int idx = tid + it * 256;
    int row = idx >> 5, c4 = idx & 31;
    int code = scodes[row];
    *(float4*)(out_q + (size_t)(row0 + row) * DDIM + c4 * 4) =
        *(const float4*)(embed + (size_t)code * DDIM + c4 * 4);
  }
}

// ---- K3: scan + EMA-size/inv (one block; histogram already done by K2).
// offs is IN: int counts (from vq_mfma atomics), OUT: exclusive offsets.
// Safe aliasing: each tid reads its own element before writing it. ----
__global__ __launch_bounds__(1024) void scan_fin(
    int* offs, const float* __restrict__ cs,
    float* __restrict__ counts_g, int* __restrict__ cursor,
    float* __restrict__ inv, float* __restrict__ out_ncs) {
  __shared__ float wtot[16], ctot[16];
  const int tid = threadIdx.x;
  const int lane = tid & 63, w = tid >> 6;
  const int cnt = offs[tid];
  const float cnum = (float)cnt;
  const float cv = cs[tid];
  float s = cnum;
  #pragma unroll
  for (int off = 1; off < 64; off <<= 1) {
    float v = __shfl_up(s, off, 64);
    if (lane >= off) s += v;
  }
  float r2 = cv;
  #pragma unroll
  for (int off = 32; off > 0; off >>= 1) r2 += __shfl_down(r2, off, 64);
  if (lane == 63) wtot[w] = s;
  if (lane == 0)  ctot[w] = r2;
  __syncthreads();
  if (tid < 16) {
    float v = wtot[tid];
    #pragma unroll
    for (int off = 1; off < 16; off <<= 1) {
      float p = __shfl_up(v, off, 64);
      if (tid >= off) v += p;
    }
    wtot[tid] = v;
    float t2 = ctot[tid];
    #pragma unroll
    for (int off = 8; off > 0; off >>= 1) t2 += __shfl_down(t2, off, 64);
    if (tid == 0) ctot[0] = t2;
  }
  __syncthreads();
  const float prefix = (w > 0) ? wtot[w - 1] : 0.f;
  const int excl = (int)(s + prefix) - cnt;
  offs[tid] = excl;
  cursor[tid] = excl;
  counts_g[tid] = cnum;
  const float ncs = cv * DECAY + OMD * cnum;
  out_ncs[tid] = ncs;
  const float total = ctot[0] * DECAY + OMD * (float)NROWS;  // sum(ncs) decomposed
  inv[tid] = (total + (float)KCODES * EPS) / ((ncs + EPS) * total);
}

// ---- K4: scatter row ids into per-code buckets (parallel, global cursors) ----
__global__ void scatter_rows(const float* __restrict__ out_ind,
                             int* __restrict__ cursor, int* __restrict__ bucket) {
  int row = blockIdx.x * 256 + threadIdx.x;
  int code = (int)out_ind[row];
  int pos = atomicAdd(cursor + code, 1);
  bucket[pos] = row;
}

// ---- K5: per-code segmented reduction + fused EMA epilogue (no out_q) ----
__global__ __launch_bounds__(256) void esum_fin(
    const int* __restrict__ bucket, const int* __restrict__ offs,
    const float* __restrict__ counts, const float* __restrict__ x,
    const float* __restrict__ ea, const float* __restrict__ inv,
    float* __restrict__ out_nea, float* __restrict__ out_ne) {
  __shared__ float4 part[512];
  const int code = blockIdx.x;
  const int t = threadIdx.x;
  const int c8 = t & 15;
  const int h = t >> 4;
  const int start = offs[code];
  const int cnt = (int)counts[code];
  float4 a0 = {0.f, 0.f, 0.f, 0.f}, a1 = {0.f, 0.f, 0.f, 0.f};
  int i = h;
  for (; i + 16 < cnt; i += 32) {
    int rowA = bucket[start + i];
    int rowB = bucket[start + i + 16];
    const float* pa = x + (size_t)rowA * DDIM + c8 * 8;
    const float* pb = x + (size_t)rowB * DDIM + c8 * 8;
    float4 xa0 = *(const float4*)(pa), xa1 = *(const float4*)(pa + 4);
    float4 xb0 = *(const float4*)(pb), xb1 = *(const float4*)(pb + 4);
    a0.x += xa0.x + xb0.x; a0.y += xa0.y + xb0.y; a0.z += xa0.z + xb0.z; a0.w += xa0.w + xb0.w;
    a1.x += xa1.x + xb1.x; a1.y += xa1.y + xb1.y; a1.z += xa1.z + xb1.z; a1.w += xa1.w + xb1.w;
  }
  for (; i < cnt; i += 16) {
    int row = bucket[start + i];
    const float* pa = x + (size_t)row * DDIM + c8 * 8;
    float4 xa0 = *(const float4*)(pa), xa1 = *(const float4*)(pa + 4);
    a0.x += xa0.x; a0.y += xa0.y; a0.z += xa0.z; a0.w += xa0.w;
    a1.x += xa1.x; a1.y += xa1.y; a1.z += xa1.z; a1.w += xa1.w;
  }
  part[h * 32 + c8 * 2]     = a0;
  part[h * 32 + c8 * 2 + 1] = a1;
  __syncthreads();
  if (t < 32) {
    float4 s = part[t];
    #pragma unroll
    for (int hh = 1; hh < 16; ++hh) {
      float4 p = part[hh * 32 + t];
      s.x += p.x; s.y += p.y; s.z += p.z; s.w += p.w;
    }
    float iv = inv[code];
    int base = code * DDIM + t * 4;
    float4 a = *(const float4*)(ea + base);
    float4 nea;
    nea.x = a.x * DECAY + OMD * s.x; nea.y = a.y * DECAY + OMD * s.y;
    nea.z = a.z * DECAY + OMD * s.z; nea.w = a.w * DECAY + OMD * s.w;
    *(float4*)(out_nea + base) = nea;
    float4 ne;
    ne.x = nea.x * iv; ne.y = nea.y * iv; ne.z = nea.z * iv; ne.w = nea.w * iv;
    *(float4*)(out_ne + base) = ne;
  }
}

extern "C" void kernel_launch(void* const* d_in, const int* in_sizes, int n_in,
                              void* d_out, int out_size, void* d_ws, size_t ws_size,
                              hipStream_t stream) {
  const float* x     = (const float*)d_in[0];
  const float* embed = (const float*)d_in[1];
  const float* cs    = (const float*)d_in[2];
  const float* ea    = (const float*)d_in[3];

  float* out     = (float*)d_out;
  float* out_q   = out;                       // 4194304
  float* out_ind = out_q + 4194304;           // 32768
  float* out_ncs = out_ind + 32768;           // 1024
  float* out_nea = out_ncs + 1024;            // 131072
  float* out_ne  = out_nea + 131072;          // 131072

  float* ws     = (float*)d_ws;
  float* counts = ws + WS_COUNTS;
  int*   offs   = (int*)(ws + WS_OFFS);       // also the int histogram
  int*   cursor = (int*)(ws + WS_CURSOR);
  float* inv    = ws + WS_INV;
  float* en2h   = ws + WS_EN2H;
  int*   bucket = (int*)(ws + WS_BUCKET);

  // epack scratch aliased into out_nea (512 KB); read only by vq_mfma,
  // overwritten later by esum_fin.
  ushort* epack = (ushort*)out_nea;

  pack_e<<<64, 256, 0, stream>>>(embed, epack, en2h, offs);
  vq_mfma<<<NROWS / 128, 256, 0, stream>>>(x, (const short8*)epack, en2h, embed,
                                           out_ind, out_q, offs);
  scan_fin<<<1, 1024, 0, stream>>>(offs, cs, counts, cursor, inv, out_ncs);
  scatter_rows<<<NROWS / 256, 256, 0, stream>>>(out_ind, cursor, bucket);
  esum_fin<<<KCODES, 256, 0, stream>>>(bucket, offs, counts, x, ea, inv,
                                       out_nea, out_ne);
}

// Round 5
// 168.047 us; speedup vs baseline: 1.1340x; 1.1340x over previous
//
#include <hip/hip_runtime.h>

#define NROWS 32768
#define DDIM  128
#define KCODES 1024
#define DECAY 0.99f
#define OMD   0.01f
#define EPS   1e-5f

typedef __attribute__((ext_vector_type(8))) short short8;
typedef __attribute__((ext_vector_type(4))) float f32x4;

// ws layout (float offsets): [counts 1024][offs i32 1024][cursor i32 1024][inv 1024][en2h 1024][bucket i32 32768]
// offs slot doubles as the int histogram (zeroed by pack_e, atomics from vq_mfma,
// read-then-overwritten per-tid by scan_fin).
#define WS_COUNTS 0
#define WS_OFFS   1024
#define WS_CURSOR 2048
#define WS_INV    3072
#define WS_EN2H   4096
#define WS_BUCKET 5120

__device__ __forceinline__ unsigned int f2bf(float f) {
  union { float f; unsigned int u; } cv; cv.f = f;
  unsigned int u = cv.u;
  return (u + 0x7fffu + ((u >> 16) & 1u)) >> 16;  // RNE
}

__device__ __forceinline__ void gload16(const void* g, void* l) {
  __builtin_amdgcn_global_load_lds(
      (const __attribute__((address_space(1))) unsigned int*)g,
      (__attribute__((address_space(3))) unsigned int*)l, 16, 0, 0);
}

// ---- K1: split embed into (eh, el) bf16, MFMA B-fragment layout + exact norms.
// 64 blocks, one 16-code tile per block, 8 floats per thread.
// epack frag (nt, j): j 0-3 = eh, j 4-7 = el. 512 KB, aliased into out_nea.
// Block 0 also zeroes the int histogram for this iteration. ----
__global__ __launch_bounds__(256) void pack_e(const float* __restrict__ embed,
                                              ushort* __restrict__ epack,
                                              float* __restrict__ en2h,
                                              int* __restrict__ cnt0) {
  const int tid = threadIdx.x;
  const int nt = blockIdx.x;
  if (nt == 0) {
    #pragma unroll
    for (int i = 0; i < 4; ++i) cnt0[tid + i * 256] = 0;
  }
  const int m = tid >> 4, s = tid & 15;     // m = code row in tile, s = k-slot
  const int kb = s >> 2, q = s & 3;
  const int row = nt * 16 + m;
  const float* ep = embed + (size_t)row * DDIM + kb * 32 + q * 8;
  float4 v0 = *(const float4*)(ep);
  float4 v1 = *(const float4*)(ep + 4);
  float v[8] = {v0.x, v0.y, v0.z, v0.w, v1.x, v1.y, v1.z, v1.w};
  unsigned int h[8], l[8];
  float ss = 0.f;
  #pragma unroll
  for (int j = 0; j < 8; ++j) {
    ss += v[j] * v[j];
    h[j] = f2bf(v[j]);
    float fh = __uint_as_float(h[j] << 16);
    l[j] = f2bf(v[j] - fh);
  }
  uint4 ph, pl;
  ph.x = h[0] | (h[1] << 16); ph.y = h[2] | (h[3] << 16);
  ph.z = h[4] | (h[5] << 16); ph.w = h[6] | (h[7] << 16);
  pl.x = l[0] | (l[1] << 16); pl.y = l[2] | (l[3] << 16);
  pl.z = l[4] | (l[5] << 16); pl.w = l[6] | (l[7] << 16);
  *(uint4*)(epack + (((size_t)nt * 8 + kb) * 64 + q * 16 + m) * 8)     = ph;  // eh
  *(uint4*)(epack + (((size_t)nt * 8 + kb + 4) * 64 + q * 16 + m) * 8) = pl;  // el
  // row norm: threads with same m are 16 consecutive lanes (s = lane&15)
  ss += __shfl_xor(ss, 1, 64);
  ss += __shfl_xor(ss, 2, 64);
  ss += __shfl_xor(ss, 4, 64);
  ss += __shfl_xor(ss, 8, 64);
  if (s == 0) en2h[row] = 0.5f * ss;
}

// ---- K2: MFMA scoring + fused quantize write + fused count histogram.
// Block = 64 rows, 8 waves = 2 code-halves x 4 row-groups. Wave (h,r) scores
// rows [r*16,+16) against codes [h*512,+512) = 32 tiles of 16. B tiles staged
// into per-half ring-4 LDS via global_load_lds (R4's verified counted-vmcnt +
// raw-barrier discipline, NEVER __syncthreads in loop). Grid 512 = 2 blk/CU =
// 16 waves/CU (4/SIMD, fixes R4's starvation); launch_bounds(512,4) pins
// VGPR<=128 for co-residency. Moves the 4 MB/CU B stream from the ~40 B/cy
// vmem-return path onto the ~85-128 B/cy LDS pipe (stage vmem only 1 MB/CU). ----
__global__ __launch_bounds__(512, 4) void vq_mfma(
    const float* __restrict__ x, const short8* __restrict__ ep8,
    const float* __restrict__ en2h, const float* __restrict__ embed,
    float* __restrict__ out_ind, float* __restrict__ out_q,
    int* __restrict__ cnt_i) {
  __shared__ short8 bfrag[2][4][512];       // per-half ring of 4 x 8 KB tiles
  __shared__ float nlds[KCODES];            // 4 KB staged 0.5*||e||^2
  __shared__ unsigned long long keys[2][64];
  __shared__ int scodes[64];
  const int tid = threadIdx.x;
  const int w = tid >> 6, lane = tid & 63;
  const int h = w >> 2, r = w & 3;          // code-half, row-group
  const int c = lane & 15, q = lane >> 4;
  const int row0 = blockIdx.x * 64;         // block's first x-row
  const int nt0 = h * 32;                   // first code tile of this half

  // A fragments from x rows [row0 + r*16, +16): xh 0-3, xl 4-7 (32 VGPRs).
  // Fully consumed into registers before staging begins.
  short8 a[8];
  {
    const float* xp = x + (size_t)(row0 + r * 16 + c) * DDIM + q * 8;
    #pragma unroll
    for (int kb = 0; kb < 4; ++kb) {
      float4 v0 = *(const float4*)(xp + kb * 32);
      float4 v1 = *(const float4*)(xp + kb * 32 + 4);
      float v[8] = {v0.x, v0.y, v0.z, v0.w, v1.x, v1.y, v1.z, v1.w};
      short8 hh, ll;
      #pragma unroll
      for (int j = 0; j < 8; ++j) {
        unsigned int hv = f2bf(v[j]);
        hh[j] = (short)hv;
        float fh = __uint_as_float(hv << 16);
        ll[j] = (short)f2bf(v[j] - fh);
      }
      a[kb] = hh;
      a[kb + 4] = ll;
    }
  }
  // norms -> LDS (lgkm, drained below)
  nlds[tid]       = en2h[tid];
  nlds[tid + 512] = en2h[tid + 512];

  __builtin_amdgcn_sched_barrier(0);
  // stage tiles 0..2 of this half: wave (h,r) stages chunk r (2 x 1 KB) of
  // each tile -> exactly 6 vmem ops outstanding per wave at loop entry.
  #pragma unroll
  for (int p = 0; p < 3; ++p) {
    gload16(ep8 + (size_t)(nt0 + p) * 512 + r * 128 + lane,
            &bfrag[h][p][r * 128]);
    gload16(ep8 + (size_t)(nt0 + p) * 512 + r * 128 + 64 + lane,
            &bfrag[h][p][r * 128 + 64]);
  }
  // drain LDS writes so the first barrier publishes nlds
  asm volatile("s_waitcnt lgkmcnt(0)" ::: "memory");

  float bestv[4]; int besti[4];
  #pragma unroll
  for (int i = 0; i < 4; ++i) { bestv[i] = -3.4e38f; besti[i] = 0; }

  // one code tile: 8 LDS b128 reads feed 12 MFMAs (3 independent chains)
  auto tile_compute = [&](int t) {
    short8 st[8];
    #pragma unroll
    for (int j = 0; j < 8; ++j) st[j] = bfrag[h][t & 3][j * 64 + lane];
    const float nh = nlds[(nt0 + t) * 16 + c];
    f32x4 accA = {-nh, -nh, -nh, -nh};      // xh . eh (norm folded in)
    f32x4 accB = {0.f, 0.f, 0.f, 0.f};     // xl . eh
    f32x4 accC = {0.f, 0.f, 0.f, 0.f};     // xh . el
    __builtin_amdgcn_s_setprio(1);
    #pragma unroll
    for (int kb = 0; kb < 4; ++kb) {
      accA = __builtin_amdgcn_mfma_f32_16x16x32_bf16(a[kb],     st[kb],     accA, 0, 0, 0);
      accB = __builtin_amdgcn_mfma_f32_16x16x32_bf16(a[kb + 4], st[kb],     accB, 0, 0, 0);
      accC = __builtin_amdgcn_mfma_f32_16x16x32_bf16(a[kb],     st[kb + 4], accC, 0, 0, 0);
    }
    __builtin_amdgcn_s_setprio(0);
    const int code = (nt0 + t) * 16 + c;
    #pragma unroll
    for (int rr = 0; rr < 4; ++rr) {        // C/D: col(code)=lane&15, row=q*4+rr
      float s = accA[rr] + accB[rr] + accC[rr];
      if (s > bestv[rr]) { bestv[rr] = s; besti[rr] = code; }
    }
  };

  // main loop: tiles 0..28, staging tile t+3 each iteration.
  // invariant at loop top: 6 loads outstanding (tiles t, t+1, t+2);
  // vmcnt(4) => own tile-t chunks landed; raw barrier => everyone's did,
  // and all waves finished reading bfrag[h][(t-1)&3] (the buf overwritten
  // by the t+3 stage below).
  for (int t = 0; t < 29; ++t) {
    asm volatile("s_waitcnt vmcnt(4)" ::: "memory");
    __builtin_amdgcn_s_barrier();
    __builtin_amdgcn_sched_barrier(0);
    const int bs = (t + 3) & 3;
    gload16(ep8 + (size_t)(nt0 + t + 3) * 512 + r * 128 + lane,
            &bfrag[h][bs][r * 128]);
    gload16(ep8 + (size_t)(nt0 + t + 3) * 512 + r * 128 + 64 + lane,
            &bfrag[h][bs][r * 128 + 64]);
    __builtin_amdgcn_sched_barrier(0);
    tile_compute(t);
  }
  // tail: tiles 29..31, draining 6 -> 4 -> 2 -> 0 outstanding
  asm volatile("s_waitcnt vmcnt(4)" ::: "memory");
  __builtin_amdgcn_s_barrier();
  __builtin_amdgcn_sched_barrier(0);
  tile_compute(29);
  asm volatile("s_waitcnt vmcnt(2)" ::: "memory");
  __builtin_amdgcn_s_barrier();
  __builtin_amdgcn_sched_barrier(0);
  tile_compute(30);
  asm volatile("s_waitcnt vmcnt(0)" ::: "memory");
  __builtin_amdgcn_s_barrier();
  __builtin_amdgcn_sched_barrier(0);
  tile_compute(31);

  // fold across the 16 code-columns (stays within each 16-lane q group)
  #pragma unroll
  for (int off = 1; off < 16; off <<= 1) {
    #pragma unroll
    for (int i = 0; i < 4; ++i) {
      float ov = __shfl_xor(bestv[i], off, 64);
      int   oi = __shfl_xor(besti[i], off, 64);
      if (ov > bestv[i] || (ov == bestv[i] && oi < besti[i])) {
        bestv[i] = ov; besti[i] = oi;       // first-max (lowest idx) ties
      }
    }
  }
  if (c == 0) {                             // 4 writer lanes per wave
    #pragma unroll
    for (int rr = 0; rr < 4; ++rr) {
      unsigned u = __float_as_uint(bestv[rr]);
      unsigned su = (u & 0x80000000u) ? ~u : (u | 0x80000000u);
      keys[h][r * 16 + q * 4 + rr] =
          ((unsigned long long)su << 32) |
          (unsigned long long)(0xFFFFFFFFu - (unsigned)besti[rr]);
    }
  }
  __syncthreads();
  if (tid < 64) {                           // merge the 2 code-halves per row
    unsigned long long k0 = keys[0][tid], k1 = keys[1][tid];
    unsigned long long k = k0 > k1 ? k0 : k1;
    int code = (int)(0xFFFFFFFFu - (unsigned)(k & 0xFFFFFFFFull));
    out_ind[row0 + tid] = (float)code;
    scodes[tid] = code;
    atomicAdd(&cnt_i[code], 1);             // fused histogram
  }
  __syncthreads();
  // fused quantize write: 64 rows x 32 float4 = 2048 float4, 4 per thread
  #pragma unroll
  for (int it = 0; it < 4; ++it) {
    int idx = tid + it * 512;
    int row = idx >> 5, c4 = idx & 31;
    int code = scodes[row];
    *(float4*)(out_q + (size_t)(row0 + row) * DDIM + c4 * 4) =
        *(const float4*)(embed + (size_t)code * DDIM + c4 * 4);
  }
}

// ---- K3: scan + EMA-size/inv (one block; histogram already done by K2).
// offs is IN: int counts (from vq_mfma atomics), OUT: exclusive offsets.
// Safe aliasing: each tid reads its own element before writing it. ----
__global__ __launch_bounds__(1024) void scan_fin(
    int* offs, const float* __restrict__ cs,
    float* __restrict__ counts_g, int* __restrict__ cursor,
    float* __restrict__ inv, float* __restrict__ out_ncs) {
  __shared__ float wtot[16], ctot[16];
  const int tid = threadIdx.x;
  const int lane = tid & 63, w = tid >> 6;
  const int cnt = offs[tid];
  const float cnum = (float)cnt;
  const float cv = cs[tid];
  float s = cnum;
  #pragma unroll
  for (int off = 1; off < 64; off <<= 1) {
    float v = __shfl_up(s, off, 64);
    if (lane >= off) s += v;
  }
  float r2 = cv;
  #pragma unroll
  for (int off = 32; off > 0; off >>= 1) r2 += __shfl_down(r2, off, 64);
  if (lane == 63) wtot[w] = s;
  if (lane == 0)  ctot[w] = r2;
  __syncthreads();
  if (tid < 16) {
    float v = wtot[tid];
    #pragma unroll
    for (int off = 1; off < 16; off <<= 1) {
      float p = __shfl_up(v, off, 64);
      if (tid >= off) v += p;
    }
    wtot[tid] = v;
    float t2 = ctot[tid];
    #pragma unroll
    for (int off = 8; off > 0; off >>= 1) t2 += __shfl_down(t2, off, 64);
    if (tid == 0) ctot[0] = t2;
  }
  __syncthreads();
  const float prefix = (w > 0) ? wtot[w - 1] : 0.f;
  const int excl = (int)(s + prefix) - cnt;
  offs[tid] = excl;
  cursor[tid] = excl;
  counts_g[tid] = cnum;
  const float ncs = cv * DECAY + OMD * cnum;
  out_ncs[tid] = ncs;
  const float total = ctot[0] * DECAY + OMD * (float)NROWS;  // sum(ncs) decomposed
  inv[tid] = (total + (float)KCODES * EPS) / ((ncs + EPS) * total);
}

// ---- K4: scatter row ids into per-code buckets (parallel, global cursors) ----
__global__ void scatter_rows(const float* __restrict__ out_ind,
                             int* __restrict__ cursor, int* __restrict__ bucket) {
  int row = blockIdx.x * 256 + threadIdx.x;
  int code = (int)out_ind[row];
  int pos = atomicAdd(cursor + code, 1);
  bucket[pos] = row;
}

// ---- K5: per-code segmented reduction + fused EMA epilogue (no out_q) ----
__global__ __launch_bounds__(256) void esum_fin(
    const int* __restrict__ bucket, const int* __restrict__ offs,
    const float* __restrict__ counts, const float* __restrict__ x,
    const float* __restrict__ ea, const float* __restrict__ inv,
    float* __restrict__ out_nea, float* __restrict__ out_ne) {
  __shared__ float4 part[512];
  const int code = blockIdx.x;
  const int t = threadIdx.x;
  const int c8 = t & 15;
  const int h = t >> 4;
  const int start = offs[code];
  const int cnt = (int)counts[code];
  float4 a0 = {0.f, 0.f, 0.f, 0.f}, a1 = {0.f, 0.f, 0.f, 0.f};
  int i = h;
  for (; i + 16 < cnt; i += 32) {
    int rowA = bucket[start + i];
    int rowB = bucket[start + i + 16];
    const float* pa = x + (size_t)rowA * DDIM + c8 * 8;
    const float* pb = x + (size_t)rowB * DDIM + c8 * 8;
    float4 xa0 = *(const float4*)(pa), xa1 = *(const float4*)(pa + 4);
    float4 xb0 = *(const float4*)(pb), xb1 = *(const float4*)(pb + 4);
    a0.x += xa0.x + xb0.x; a0.y += xa0.y + xb0.y; a0.z += xa0.z + xb0.z; a0.w += xa0.w + xb0.w;
    a1.x += xa1.x + xb1.x; a1.y += xa1.y + xb1.y; a1.z += xa1.z + xb1.z; a1.w += xa1.w + xb1.w;
  }
  for (; i < cnt; i += 16) {
    int row = bucket[start + i];
    const float* pa = x + (size_t)row * DDIM + c8 * 8;
    float4 xa0 = *(const float4*)(pa), xa1 = *(const float4*)(pa + 4);
    a0.x += xa0.x; a0.y += xa0.y; a0.z += xa0.z; a0.w += xa0.w;
    a1.x += xa1.x; a1.y += xa1.y; a1.z += xa1.z; a1.w += xa1.w;
  }
  part[h * 32 + c8 * 2]     = a0;
  part[h * 32 + c8 * 2 + 1] = a1;
  __syncthreads();
  if (t < 32) {
    float4 s = part[t];
    #pragma unroll
    for (int hh = 1; hh < 16; ++hh) {
      float4 p = part[hh * 32 + t];
      s.x += p.x; s.y += p.y; s.z += p.z; s.w += p.w;
    }
    float iv = inv[code];
    int base = code * DDIM + t * 4;
    float4 a = *(const float4*)(ea + base);
    float4 nea;
    nea.x = a.x * DECAY + OMD * s.x; nea.y = a.y * DECAY + OMD * s.y;
    nea.z = a.z * DECAY + OMD * s.z; nea.w = a.w * DECAY + OMD * s.w;
    *(float4*)(out_nea + base) = nea;
    float4 ne;
    ne.x = nea.x * iv; ne.y = nea.y * iv; ne.z = nea.z * iv; ne.w = nea.w * iv;
    *(float4*)(out_ne + base) = ne;
  }
}

extern "C" void kernel_launch(void* const* d_in, const int* in_sizes, int n_in,
                              void* d_out, int out_size, void* d_ws, size_t ws_size,
                              hipStream_t stream) {
  const float* x     = (const float*)d_in[0];
  const float* embed = (const float*)d_in[1];
  const float* cs    = (const float*)d_in[2];
  const float* ea    = (const float*)d_in[3];

  float* out     = (float*)d_out;
  float* out_q   = out;                       // 4194304
  float* out_ind = out_q + 4194304;           // 32768
  float* out_ncs = out_ind + 32768;           // 1024
  float* out_nea = out_ncs + 1024;            // 131072
  float* out_ne  = out_nea + 131072;          // 131072

  float* ws     = (float*)d_ws;
  float* counts = ws + WS_COUNTS;
  int*   offs   = (int*)(ws + WS_OFFS);       // also the int histogram
  int*   cursor = (int*)(ws + WS_CURSOR);
  float* inv    = ws + WS_INV;
  float* en2h   = ws + WS_EN2H;
  int*   bucket = (int*)(ws + WS_BUCKET);

  // epack scratch aliased into out_nea (512 KB); read only by vq_mfma,
  // overwritten later by esum_fin.
  ushort* epack = (ushort*)out_nea;

  pack_e<<<64, 256, 0, stream>>>(embed, epack, en2h, offs);
  vq_mfma<<<NROWS / 64, 512, 0, stream>>>(x, (const short8*)epack, en2h, embed,
                                          out_ind, out_q, offs);
  scan_fin<<<1, 1024, 0, stream>>>(offs, cs, counts, cursor, inv, out_ncs);
  scatter_rows<<<NROWS / 256, 256, 0, stream>>>(out_ind, cursor, bucket);
  esum_fin<<<KCODES, 256, 0, stream>>>(bucket, offs, counts, x, ea, inv,
                                       out_nea, out_ne);
}